// Round 7
// baseline (63.745 us; speedup 1.0000x reference)
//
#include <hip/hip_runtime.h>
#include <hip/hip_bf16.h>

#define H 1024
#define V 50257
#define L 100
#define NDB 2048   // kD grid: 2048 blocks x 4 waves = 8192 waves

// ---------- helpers ----------

__device__ __forceinline__ float wave_sum(float v) {
    #pragma unroll
    for (int off = 32; off > 0; off >>= 1) v += __shfl_down(v, off, 64);
    return v;
}

__device__ __forceinline__ float dot1024(const float4* w, const float4* x, int lane) {
    float acc = 0.f;
    #pragma unroll
    for (int j = 0; j < 4; j++) {
        float4 a = w[lane + 64 * j];
        float4 b = x[lane + 64 * j];
        acc += a.x * b.x + a.y * b.y + a.z * b.z + a.w * b.w;
    }
    return acc;
}

// ---------- k1: attn logits (blocks 0..24, wave/row) + gh rows (blocks 25..792) ----------

__global__ void k1_head(const int* token, const float* hidden, const float* embedding,
                        const float* attn_w, const float* attn_b,
                        const float* w_hh, const float* b_hh,
                        float* ws_log, float* ws_gh) {
    int lane = threadIdx.x & 63, wv = threadIdx.x >> 6;
    const float4* e4 = (const float4*)(embedding + (size_t)token[0] * H);
    const float4* h4 = (const float4*)hidden;
    if (blockIdx.x < 25) {
        int r = blockIdx.x * 4 + wv;               // 0..99
        const float4* wr = (const float4*)(attn_w + (size_t)r * (2 * H));
        float acc = dot1024(wr, e4, lane) + dot1024(wr + 256, h4, lane);
        acc = wave_sum(acc);
        if (lane == 0) ws_log[r] = acc + attn_b[r];
    } else {
        int r = (blockIdx.x - 25) * 4 + wv;        // 0..3071
        const float4* wr = (const float4*)(w_hh + (size_t)r * H);
        float acc = wave_sum(dot1024(wr, h4, lane));
        if (lane == 0) ws_gh[r] = acc + b_hh[r];
    }
}

// ---------- k2: softmax (redundant, shfl-parallel) + apply (redundant, coalesced)
//              + combine+relu (8 rows per block). grid 128 x 256. ----------

__global__ void k2_mid(const int* token, const float* ws_log, const float* enc,
                       const float* embedding, const float* comb_w, const float* comb_b,
                       float* ws_x, float* out_attnw) {
    __shared__ float red[8];
    __shared__ float aw[128];
    __shared__ float4 app4[256];
    int t = threadIdx.x, lane = t & 63, wv = t >> 6;

    // softmax over 100 logits, wave-parallel
    float x = (t < L) ? ws_log[t] : -1e30f;
    float mv = x;
    #pragma unroll
    for (int off = 32; off > 0; off >>= 1) mv = fmaxf(mv, __shfl_down(mv, off, 64));
    if (lane == 0) red[wv] = mv;
    __syncthreads();
    float m = fmaxf(fmaxf(red[0], red[1]), fmaxf(red[2], red[3]));
    float e = (t < L) ? expf(x - m) : 0.f;
    float sv = wave_sum(e);
    if (lane == 0) red[4 + wv] = sv;
    __syncthreads();
    float s = red[4] + red[5] + red[6] + red[7];
    float a = e / s;
    if (t < 128) aw[t] = a;                        // zero past L
    if (blockIdx.x == 0 && t < L) out_attnw[t] = a;
    __syncthreads();

    // apply: thread t owns float4 column t; 100 independent coalesced loads
    {
        const float4* enc4 = (const float4*)enc;
        float4 acc4 = make_float4(0.f, 0.f, 0.f, 0.f);
        #pragma unroll 4
        for (int l = 0; l < L; l++) {
            float w = aw[l];
            float4 ev = enc4[l * 256 + t];
            acc4.x += w * ev.x; acc4.y += w * ev.y;
            acc4.z += w * ev.z; acc4.w += w * ev.w;
        }
        app4[t] = acc4;
    }
    __syncthreads();

    // combine + relu: 8 rows per block, 2 per wave
    const float4* e4 = (const float4*)(embedding + (size_t)token[0] * H);
    #pragma unroll
    for (int k = 0; k < 2; k++) {
        int r = blockIdx.x * 8 + wv * 2 + k;       // 0..1023
        const float4* wr = (const float4*)(comb_w + (size_t)r * (2 * H));
        float acc = dot1024(wr, e4, lane) + dot1024(wr + 256, app4, lane);
        acc = wave_sum(acc);
        if (lane == 0) ws_x[r] = fmaxf(acc + comb_b[r], 0.0f);
    }
}

// ---------- k3: gi = w_ih @ x; gates -> h_new (wave per hidden unit) ----------

__global__ void k3_gru(const float* ws_x, const float* hidden, const float* ws_gh,
                       const float* w_ih, const float* b_ih, const float* b_hh,
                       float* out_h, float* ws_hn) {
    int lane = threadIdx.x & 63, wv = threadIdx.x >> 6;
    int h = blockIdx.x * 4 + wv;                  // 0..1023
    const float4* x4 = (const float4*)ws_x;
    float a0 = dot1024((const float4*)(w_ih + (size_t)h * H), x4, lane);
    float a1 = dot1024((const float4*)(w_ih + (size_t)(H + h) * H), x4, lane);
    float a2 = dot1024((const float4*)(w_ih + (size_t)(2 * H + h) * H), x4, lane);
    a0 = wave_sum(a0); a1 = wave_sum(a1); a2 = wave_sum(a2);
    if (lane == 0) {
        float ir = a0 + b_ih[h], iz = a1 + b_ih[H + h], in_ = a2 + b_ih[2 * H + h];
        float hr = ws_gh[h] , hz = ws_gh[H + h],  hn = ws_gh[2 * H + h];
        float r = 1.f / (1.f + expf(-(ir + hr)));
        float z = 1.f / (1.f + expf(-(iz + hz)));
        float n = tanhf(in_ + r * hn);
        float h0 = hidden[h];
        float v = (1.f - z) * n + z * h0;
        out_h[h] = v;
        ws_hn[h] = v;
    }
}

// ---------- kD: logits = h_new @ out_w.T + out_b, 2 rows/wave/iter, 8192 waves ----------

__global__ void kD_outproj(const float* hn, const float* out_w, const float* out_b,
                           float* out_logits, float* ws_pm, float* ws_ps) {
    __shared__ float sm[4], ss[4];
    int lane = threadIdx.x & 63;
    int wv   = threadIdx.x >> 6;
    const float4* h4 = (const float4*)hn;
    float4 h0 = h4[lane], h1 = h4[lane + 64], h2 = h4[lane + 128], h3 = h4[lane + 192];
    float m = -1e30f, s = 0.f;
    int wid = blockIdx.x * 4 + wv;                // 0..8191
    for (int r0 = wid * 2; r0 < V; r0 += NDB * 8) {
        float acc[2] = {0.f, 0.f};
        #pragma unroll
        for (int i = 0; i < 2; i++) {
            int r = r0 + i;
            if (r < V) {
                const float4* wr = (const float4*)(out_w + (size_t)r * H);
                float4 a = wr[lane], b = wr[lane + 64], c = wr[lane + 128], d = wr[lane + 192];
                acc[i] = a.x * h0.x + a.y * h0.y + a.z * h0.z + a.w * h0.w
                       + b.x * h1.x + b.y * h1.y + b.z * h1.z + b.w * h1.w
                       + c.x * h2.x + c.y * h2.y + c.z * h2.z + c.w * h2.w
                       + d.x * h3.x + d.y * h3.y + d.z * h3.z + d.w * h3.w;
            }
        }
        #pragma unroll
        for (int off = 32; off > 0; off >>= 1) {
            acc[0] += __shfl_down(acc[0], off, 64);
            acc[1] += __shfl_down(acc[1], off, 64);
        }
        if (lane == 0) {
            #pragma unroll
            for (int i = 0; i < 2; i++) {
                int r = r0 + i;
                if (r < V) {
                    float lg = acc[i] + out_b[r];
                    out_logits[r] = lg;
                    float nm = fmaxf(m, lg);
                    s = s * expf(m - nm) + expf(lg - nm);
                    m = nm;
                }
            }
        }
    }
    if (lane == 0) { sm[wv] = m; ss[wv] = s; }
    __syncthreads();
    if (threadIdx.x == 0) {
        m = sm[0]; s = ss[0];
        #pragma unroll
        for (int i = 1; i < 4; i++) {
            float nm = fmaxf(m, sm[i]);
            s = s * expf(m - nm) + ss[i] * expf(sm[i] - nm);
            m = nm;
        }
        ws_pm[blockIdx.x] = m;
        ws_ps[blockIdx.x] = s;
    }
}

// ---------- kE: reduce NDB partials (redundant per block) + in-place log_softmax ----------

__global__ void kE_finalize(const float* ws_pm, const float* ws_ps, float* out) {
    __shared__ float sm[4], ss[4], fm, fs;
    int t = threadIdx.x;
    float m = -1e30f, s = 0.f;
    for (int i = t; i < NDB; i += 256) {
        float pm = ws_pm[i], ps = ws_ps[i];
        float nm = fmaxf(m, pm);
        s = s * expf(m - nm) + ps * expf(pm - nm);
        m = nm;
    }
    #pragma unroll
    for (int off = 32; off > 0; off >>= 1) {
        float om = __shfl_down(m, off, 64);
        float os = __shfl_down(s, off, 64);
        float nm = fmaxf(m, om);
        s = s * expf(m - nm) + os * expf(om - nm);
        m = nm;
    }
    int lane = t & 63, wv = t >> 6;
    if (lane == 0) { sm[wv] = m; ss[wv] = s; }
    __syncthreads();
    if (t == 0) {
        m = sm[0]; s = ss[0];
        #pragma unroll
        for (int i = 1; i < 4; i++) {
            float nm = fmaxf(m, sm[i]);
            s = s * expf(m - nm) + ss[i] * expf(sm[i] - nm);
            m = nm;
        }
        fm = m; fs = logf(s);
    }
    __syncthreads();
    float M = fm, LS = fs;
    for (int v = blockIdx.x * 256 + t; v < V; v += gridDim.x * 256)
        out[v] = out[v] - M - LS;
}

// ---------- launch ----------

extern "C" void kernel_launch(void* const* d_in, const int* in_sizes, int n_in,
                              void* d_out, int out_size, void* d_ws, size_t ws_size,
                              hipStream_t stream) {
    const int*   token     = (const int*)d_in[0];
    const float* hidden    = (const float*)d_in[1];
    const float* enc       = (const float*)d_in[2];
    const float* embedding = (const float*)d_in[3];
    const float* attn_w    = (const float*)d_in[4];
    const float* attn_b    = (const float*)d_in[5];
    const float* comb_w    = (const float*)d_in[6];
    const float* comb_b    = (const float*)d_in[7];
    const float* w_ih      = (const float*)d_in[8];
    const float* w_hh      = (const float*)d_in[9];
    const float* b_ih      = (const float*)d_in[10];
    const float* b_hh      = (const float*)d_in[11];
    const float* out_w     = (const float*)d_in[12];
    const float* out_b     = (const float*)d_in[13];

    float* out = (float*)d_out;           // [0,V) log_softmax | [V,V+H) h_new | [V+H,V+H+L) attn_w
    float* ws  = (float*)d_ws;
    float* ws_log = ws;                   // 100   @ 0
    float* ws_gh  = ws + 128;             // 3072  @ 128
    float* ws_x   = ws + 3200;            // 1024  @ 3200
    float* ws_pm  = ws + 4224;            // 2048  @ 4224
    float* ws_ps  = ws + 6272;            // 2048  @ 6272
    float* ws_hn  = ws + 8320;            // 1024  @ 8320

    k1_head<<<dim3(793), dim3(256), 0, stream>>>(token, hidden, embedding,
                                                 attn_w, attn_b, w_hh, b_hh,
                                                 ws_log, ws_gh);
    k2_mid<<<dim3(128), dim3(256), 0, stream>>>(token, ws_log, enc, embedding,
                                                comb_w, comb_b, ws_x, out + V + H);
    k3_gru<<<dim3(256), dim3(256), 0, stream>>>(ws_x, hidden, ws_gh, w_ih, b_ih, b_hh,
                                                out + V, ws_hn);
    kD_outproj<<<dim3(NDB), dim3(256), 0, stream>>>(ws_hn, out_w, out_b, out, ws_pm, ws_ps);
    kE_finalize<<<dim3(128), dim3(256), 0, stream>>>(ws_pm, ws_ps, out);
}

// Round 8
// 56.960 us; speedup vs baseline: 1.1191x; 1.1191x over previous
//
#include <hip/hip_runtime.h>
#include <hip/hip_bf16.h>

#define H 1024
#define V 50257
#define L 100
#define NDB 2048   // kD grid: 2048 blocks x 4 waves = 8192 waves

// ---------- helpers ----------

__device__ __forceinline__ float wave_sum(float v) {
    #pragma unroll
    for (int off = 32; off > 0; off >>= 1) v += __shfl_down(v, off, 64);
    return v;
}

__device__ __forceinline__ float dot1024(const float4* w, const float4* x, int lane) {
    float acc = 0.f;
    #pragma unroll
    for (int j = 0; j < 4; j++) {
        float4 a = w[lane + 64 * j];
        float4 b = x[lane + 64 * j];
        acc += a.x * b.x + a.y * b.y + a.z * b.z + a.w * b.w;
    }
    return acc;
}

// ---------- k1: attn logits (blocks 0..24) + gh = w_hh @ h0 + b_hh (blocks 25..792) ----------

__global__ void k1_head(const int* token, const float* hidden, const float* embedding,
                        const float* attn_w, const float* attn_b,
                        const float* w_hh, const float* b_hh,
                        float* ws_log, float* ws_gh) {
    int lane = threadIdx.x & 63, wv = threadIdx.x >> 6;
    const float4* h4 = (const float4*)hidden;
    if (blockIdx.x < 25) {
        const float4* e4 = (const float4*)(embedding + (size_t)token[0] * H);
        int r = blockIdx.x * 4 + wv;               // 0..99
        const float4* wr = (const float4*)(attn_w + (size_t)r * (2 * H));
        float acc = dot1024(wr, e4, lane) + dot1024(wr + 256, h4, lane);
        acc = wave_sum(acc);
        if (lane == 0) ws_log[r] = acc + attn_b[r];
    } else {
        int r = (blockIdx.x - 25) * 4 + wv;        // 0..3071
        const float4* wr = (const float4*)(w_hh + (size_t)r * H);
        float acc = wave_sum(dot1024(wr, h4, lane));
        if (lane == 0) ws_gh[r] = acc + b_hh[r];
    }
}

// ---------- kS: parallel softmax + l-parallel attn_applied (16 blocks) ----------

__global__ void kS_softmax_apply(const float* ws_log, const float* enc,
                                 float* ws_app, float* out_attnw) {
    __shared__ float red[8];
    __shared__ float aw_s[128];
    __shared__ float part[4][64];
    int t = threadIdx.x, lane = t & 63, wv = t >> 6;

    float x = (t < L) ? ws_log[t] : -1e30f;
    float mv = x;
    #pragma unroll
    for (int off = 32; off > 0; off >>= 1) mv = fmaxf(mv, __shfl_down(mv, off, 64));
    if (lane == 0) red[wv] = mv;
    __syncthreads();
    float m = fmaxf(fmaxf(red[0], red[1]), fmaxf(red[2], red[3]));
    float e = (t < L) ? expf(x - m) : 0.f;
    float sv = wave_sum(e);
    if (lane == 0) red[4 + wv] = sv;
    __syncthreads();
    float s = red[4] + red[5] + red[6] + red[7];
    float aw = e / s;
    if (t < 128) aw_s[t] = aw;                    // zero-padded past L
    if (blockIdx.x == 0 && t < L) out_attnw[t] = aw;
    __syncthreads();

    int h = blockIdx.x * 64 + lane;
    float acc = 0.f;
    #pragma unroll
    for (int i = 0; i < 25; i++) {
        int l = wv * 25 + i;
        acc += aw_s[l] * enc[l * H + h];
    }
    part[wv][lane] = acc;
    __syncthreads();
    if (wv == 0)
        ws_app[h] = part[0][lane] + part[1][lane] + part[2][lane] + part[3][lane];
}

// ---------- kComb: x = relu(concat(emb, applied) @ comb_w.T + comb_b), wave per row ----------

__global__ void kComb(const int* token, const float* embedding, const float* ws_app,
                      const float* comb_w, const float* comb_b, float* ws_x) {
    int lane = threadIdx.x & 63, wv = threadIdx.x >> 6;
    int r = blockIdx.x * 4 + wv;                  // grid 256 -> 1024 rows
    const float4* e4 = (const float4*)(embedding + (size_t)token[0] * H);
    const float4* a4 = (const float4*)ws_app;
    const float4* wr = (const float4*)(comb_w + (size_t)r * (2 * H));
    float acc = dot1024(wr, e4, lane) + dot1024(wr + 256, a4, lane);
    acc = wave_sum(acc);
    if (lane == 0) ws_x[r] = fmaxf(acc + comb_b[r], 0.0f);
}

// ---------- k3: gi = w_ih @ x; gates -> h_new (wave per hidden unit) ----------

__global__ void k3_gru(const float* ws_x, const float* hidden, const float* ws_gh,
                       const float* w_ih, const float* b_ih, const float* b_hh,
                       float* out_h, float* ws_hn) {
    int lane = threadIdx.x & 63, wv = threadIdx.x >> 6;
    int h = blockIdx.x * 4 + wv;                  // 0..1023
    const float4* x4 = (const float4*)ws_x;
    float a0 = dot1024((const float4*)(w_ih + (size_t)h * H), x4, lane);
    float a1 = dot1024((const float4*)(w_ih + (size_t)(H + h) * H), x4, lane);
    float a2 = dot1024((const float4*)(w_ih + (size_t)(2 * H + h) * H), x4, lane);
    a0 = wave_sum(a0); a1 = wave_sum(a1); a2 = wave_sum(a2);
    if (lane == 0) {
        float ir = a0 + b_ih[h], iz = a1 + b_ih[H + h], in_ = a2 + b_ih[2 * H + h];
        float hr = ws_gh[h] , hz = ws_gh[H + h],  hn = ws_gh[2 * H + h];
        float r = 1.f / (1.f + expf(-(ir + hr)));
        float z = 1.f / (1.f + expf(-(iz + hz)));
        float n = tanhf(in_ + r * hn);
        float h0 = hidden[h];
        float v = (1.f - z) * n + z * h0;
        out_h[h] = v;
        ws_hn[h] = v;
    }
}

// ---------- kD: logits = h_new @ out_w.T + out_b, 2 rows/wave/iter, 8192 waves ----------

__global__ void kD_outproj(const float* hn, const float* out_w, const float* out_b,
                           float* out_logits, float* ws_pm, float* ws_ps) {
    __shared__ float sm[4], ss[4];
    int lane = threadIdx.x & 63;
    int wv   = threadIdx.x >> 6;
    const float4* h4 = (const float4*)hn;
    float4 h0 = h4[lane], h1 = h4[lane + 64], h2 = h4[lane + 128], h3 = h4[lane + 192];
    float m = -1e30f, s = 0.f;
    int wid = blockIdx.x * 4 + wv;                // 0..8191
    for (int r0 = wid * 2; r0 < V; r0 += NDB * 8) {
        float acc[2] = {0.f, 0.f};
        #pragma unroll
        for (int i = 0; i < 2; i++) {
            int r = r0 + i;
            if (r < V) {
                const float4* wr = (const float4*)(out_w + (size_t)r * H);
                float4 a = wr[lane], b = wr[lane + 64], c = wr[lane + 128], d = wr[lane + 192];
                acc[i] = a.x * h0.x + a.y * h0.y + a.z * h0.z + a.w * h0.w
                       + b.x * h1.x + b.y * h1.y + b.z * h1.z + b.w * h1.w
                       + c.x * h2.x + c.y * h2.y + c.z * h2.z + c.w * h2.w
                       + d.x * h3.x + d.y * h3.y + d.z * h3.z + d.w * h3.w;
            }
        }
        #pragma unroll
        for (int off = 32; off > 0; off >>= 1) {
            acc[0] += __shfl_down(acc[0], off, 64);
            acc[1] += __shfl_down(acc[1], off, 64);
        }
        if (lane == 0) {
            #pragma unroll
            for (int i = 0; i < 2; i++) {
                int r = r0 + i;
                if (r < V) {
                    float lg = acc[i] + out_b[r];
                    out_logits[r] = lg;
                    float nm = fmaxf(m, lg);
                    s = s * expf(m - nm) + expf(lg - nm);
                    m = nm;
                }
            }
        }
    }
    if (lane == 0) { sm[wv] = m; ss[wv] = s; }
    __syncthreads();
    if (threadIdx.x == 0) {
        m = sm[0]; s = ss[0];
        #pragma unroll
        for (int i = 1; i < 4; i++) {
            float nm = fmaxf(m, sm[i]);
            s = s * expf(m - nm) + ss[i] * expf(sm[i] - nm);
            m = nm;
        }
        ws_pm[blockIdx.x] = m;
        ws_ps[blockIdx.x] = s;
    }
}

// ---------- kE: reduce NDB partials (redundant per block) + in-place log_softmax ----------

__global__ void kE_finalize(const float* ws_pm, const float* ws_ps, float* out) {
    __shared__ float sm[4], ss[4], fm, fs;
    int t = threadIdx.x;
    float m = -1e30f, s = 0.f;
    for (int i = t; i < NDB; i += 256) {
        float pm = ws_pm[i], ps = ws_ps[i];
        float nm = fmaxf(m, pm);
        s = s * expf(m - nm) + ps * expf(pm - nm);
        m = nm;
    }
    #pragma unroll
    for (int off = 32; off > 0; off >>= 1) {
        float om = __shfl_down(m, off, 64);
        float os = __shfl_down(s, off, 64);
        float nm = fmaxf(m, om);
        s = s * expf(m - nm) + os * expf(om - nm);
        m = nm;
    }
    int lane = t & 63, wv = t >> 6;
    if (lane == 0) { sm[wv] = m; ss[wv] = s; }
    __syncthreads();
    if (t == 0) {
        m = sm[0]; s = ss[0];
        #pragma unroll
        for (int i = 1; i < 4; i++) {
            float nm = fmaxf(m, sm[i]);
            s = s * expf(m - nm) + ss[i] * expf(sm[i] - nm);
            m = nm;
        }
        fm = m; fs = logf(s);
    }
    __syncthreads();
    float M = fm, LS = fs;
    for (int v = blockIdx.x * 256 + t; v < V; v += gridDim.x * 256)
        out[v] = out[v] - M - LS;
}

// ---------- launch ----------

extern "C" void kernel_launch(void* const* d_in, const int* in_sizes, int n_in,
                              void* d_out, int out_size, void* d_ws, size_t ws_size,
                              hipStream_t stream) {
    const int*   token     = (const int*)d_in[0];
    const float* hidden    = (const float*)d_in[1];
    const float* enc       = (const float*)d_in[2];
    const float* embedding = (const float*)d_in[3];
    const float* attn_w    = (const float*)d_in[4];
    const float* attn_b    = (const float*)d_in[5];
    const float* comb_w    = (const float*)d_in[6];
    const float* comb_b    = (const float*)d_in[7];
    const float* w_ih      = (const float*)d_in[8];
    const float* w_hh      = (const float*)d_in[9];
    const float* b_ih      = (const float*)d_in[10];
    const float* b_hh      = (const float*)d_in[11];
    const float* out_w     = (const float*)d_in[12];
    const float* out_b     = (const float*)d_in[13];

    float* out = (float*)d_out;           // [0,V) log_softmax | [V,V+H) h_new | [V+H,V+H+L) attn_w
    float* ws  = (float*)d_ws;
    float* ws_log = ws;                   // 100   @ 0
    float* ws_gh  = ws + 128;             // 3072  @ 128
    float* ws_app = ws + 3200;            // 1024  @ 3200
    float* ws_x   = ws + 4224;            // 1024  @ 4224
    float* ws_pm  = ws + 5248;            // 2048  @ 5248
    float* ws_ps  = ws + 7296;            // 2048  @ 7296
    float* ws_hn  = ws + 9344;            // 1024  @ 9344

    k1_head<<<dim3(793), dim3(256), 0, stream>>>(token, hidden, embedding,
                                                 attn_w, attn_b, w_hh, b_hh,
                                                 ws_log, ws_gh);
    kS_softmax_apply<<<dim3(16), dim3(256), 0, stream>>>(ws_log, enc, ws_app, out + V + H);
    kComb<<<dim3(256), dim3(256), 0, stream>>>(token, embedding, ws_app,
                                               comb_w, comb_b, ws_x);
    k3_gru<<<dim3(256), dim3(256), 0, stream>>>(ws_x, hidden, ws_gh, w_ih, b_ih, b_hh,
                                                out + V, ws_hn);
    kD_outproj<<<dim3(NDB), dim3(256), 0, stream>>>(ws_hn, out_w, out_b, out, ws_pm, ws_ps);
    kE_finalize<<<dim3(128), dim3(256), 0, stream>>>(ws_pm, ws_ps, out);
}